// Round 6
// baseline (123.122 us; speedup 1.0000x reference)
//
#include <hip/hip_runtime.h>
#include <hip/hip_bf16.h>

#define NQ    8
#define HID   768
#define BATCH 8192
#define SPB   4                      // 4 waves/block, 1 sample per wave
#define NBLK  (BATCH / SPB)          // 2048
#define TPB   256

// ---------- dtype-generic load/store ----------
template<int BF> __device__ __forceinline__ float LDV(const void* p, int i) {
    if constexpr (BF) return __bfloat162float(((const __hip_bfloat16*)p)[i]);
    else return ((const float*)p)[i];
}
template<int BF> __device__ __forceinline__ float4 LD4(const void* p, int i4) {
    if constexpr (BF) {
        ushort4 v = ((const ushort4*)p)[i4];
        float4 r;
        r.x = __uint_as_float(((unsigned)v.x) << 16);
        r.y = __uint_as_float(((unsigned)v.y) << 16);
        r.z = __uint_as_float(((unsigned)v.z) << 16);
        r.w = __uint_as_float(((unsigned)v.w) << 16);
        return r;
    } else {
        return ((const float4*)p)[i4];
    }
}
template<int BF> __device__ __forceinline__ void ST4(void* p, int i4, float4 v) {
    if constexpr (BF) {
        __hip_bfloat16 bx = __float2bfloat16(v.x);
        __hip_bfloat16 by = __float2bfloat16(v.y);
        __hip_bfloat16 bz = __float2bfloat16(v.z);
        __hip_bfloat16 bw = __float2bfloat16(v.w);
        ushort4 s;
        s.x = *(const unsigned short*)&bx;
        s.y = *(const unsigned short*)&by;
        s.z = *(const unsigned short*)&bz;
        s.w = *(const unsigned short*)&bw;
        ((ushort4*)p)[i4] = s;
    } else {
        ((float4*)p)[i4] = v;
    }
}

// ---------- VALU cross-lane primitives (no DS pipe) ----------
// DPP ctrl: quad_perm xor1 = 0xB1, quad_perm xor2 = 0x4E,
//           row_half_mirror = 0x141 (xor-4-equiv pairing),
//           row_mirror = 0x140 (xor-8-equiv pairing within 16)
template<int CTRL>
__device__ __forceinline__ float dpp_mov(float x) {
    int xi = __float_as_int(x);
    int yi = __builtin_amdgcn_update_dpp(xi, xi, CTRL, 0xF, 0xF, false);
    return __int_as_float(yi);
}
__device__ __forceinline__ float rl(float x, int l) {   // l must be constant
    return __int_as_float(__builtin_amdgcn_readlane(__float_as_int(x), l));
}

// ---------- fused single kernel: 1 wave = 1 sample, ZERO DS ops ----------
// lane = 8*j + u : group j owns qubit j; sublane u covers i4 = u + 8t.
template<int BF>
__device__ __forceinline__ void run_all(
    const void* hidden_, const void* W_in_, const void* b_in_,
    const void* W_out_, const void* b_out_, const void* wry_, const void* wrz_,
    const void* gamma_, const void* beta_, void* out_)
{
    const int tid  = threadIdx.x;
    const int lane = tid & 63;
    const int wv   = tid >> 6;
    const int j    = lane >> 3;
    const int u    = lane & 7;
    const int b    = blockIdx.x * SPB + wv;

    // ---- per-lane circuit constants for qubit j (branch-free) ----
    float DA, DB, Kr, Ki;
    {
        float ry0 = LDV<BF>(wry_, j), ry1 = LDV<BF>(wry_, NQ + j);
        float rz0 = LDV<BF>(wrz_, j), rz1 = LDV<BF>(wrz_, NQ + j);
        float cA = cosf(0.5f*ry0), sA = sinf(0.5f*ry0);
        float cB = cosf(0.5f*ry1), sB = sinf(0.5f*ry1);
        float p0c = cosf(0.5f*rz0), p0s = sinf(0.5f*rz0);
        float p1c = cosf(0.5f*rz1), p1s = sinf(0.5f*rz1);
        float g00r =  cA*p0c, g00i = -cA*p0s;
        float g01r = -sA*p0c, g01i =  sA*p0s;
        float g10r =  sA*p0c, g10i =  sA*p0s;
        float g11r =  cA*p0c, g11i =  cA*p0s;
        float h00r = cB*g00r - sB*g10r, h00i = cB*g00i - sB*g10i;
        float h01r = cB*g01r - sB*g11r, h01i = cB*g01i - sB*g11i;
        float h10r = sB*g00r + cB*g10r, h10i = sB*g00i + cB*g10i;
        float h11r = sB*g01r + cB*g11r, h11i = sB*g01i + cB*g11i;
        float f00r = h00r*p1c + h00i*p1s, f00i = h00i*p1c - h00r*p1s;
        float f01r = h01r*p1c + h01i*p1s, f01i = h01i*p1c - h01r*p1s;
        float f10r = h10r*p1c - h10i*p1s, f10i = h10i*p1c + h10r*p1s;
        float f11r = h11r*p1c - h11i*p1s, f11i = h11i*p1c + h11r*p1s;
        DA = f00r*f00r + f00i*f00i - (f10r*f10r + f10i*f10i);
        DB = f01r*f01r + f01i*f01i - (f11r*f11r + f11i*f11i);
        Kr = (f00r*f01r + f00i*f01i) - (f10r*f11r + f10i*f11i);
        Ki = (f00i*f01r - f00r*f01i) - (f10i*f11r - f10r*f11i);
    }

    // ---- phase A: group j computes <hidden_b, W_in_j> (R1 layout) ----
    float a0=0.f, a1=0.f, a2=0.f, a3=0.f;
    const int hb = b * (HID/4);
    const int wb = j * (HID/4);
    #pragma unroll
    for (int t = 0; t < 24; ++t) {
        int i4 = u + (t << 3);
        float4 h = LD4<BF>(hidden_, hb + i4);
        float4 w = LD4<BF>(W_in_,  wb + i4);
        a0 = fmaf(h.x, w.x, a0); a1 = fmaf(h.y, w.y, a1);
        a2 = fmaf(h.z, w.z, a2); a3 = fmaf(h.w, w.w, a3);
    }
    float acc = (a0 + a1) + (a2 + a3);
    // reduce across the 8 sublanes: all-VALU (quad xor1, xor2, half-mirror)
    acc += dpp_mov<0xB1>(acc);
    acc += dpp_mov<0x4E>(acc);
    acc += dpp_mov<0x141>(acc);

    // ---- circuit: one tanh/sinpi/cospi per lane ----
    float zb = acc + LDV<BF>(b_in_, j);
    float th = tanhf(zb);
    float sj = sinpif(th), cj = cospif(th);

    float ca = 0.5f * (DA + DB), da = 0.5f * (DA - DB);
    const bool g0 = (j == 0);
    float uu = da * cj;
    float vv = fmaf(Kr, sj, ca);
    float MA = g0 ? 1.f : (vv + uu), MB = g0 ? 1.f : (vv - uu);
    float fr = g0 ? 1.f : Kr,        fi = g0 ? 0.f : (cj * Ki);
    // pair-product across group pairs {2r,2r+1} via row_mirror (VALU)
    MA *= dpp_mov<0x140>(MA);
    MB *= dpp_mov<0x140>(MB);
    {
        float qr = dpp_mov<0x140>(fr), qi = dpp_mov<0x140>(fi);
        float nr = fr*qr - fi*qi, ni = fr*qi + fi*qr;
        fr = nr; fi = ni;
    }
    // rows (16 lanes) now uniform; combine 4 row values via readlane (SGPR)
    float PA = (rl(MA,0)*rl(MA,16)) * (rl(MA,32)*rl(MA,48));
    float PB = (rl(MB,0)*rl(MB,16)) * (rl(MB,32)*rl(MB,48));
    float PFr, PFi;
    {
        float ar = rl(fr, 0), ai = rl(fi, 0);
        float br = rl(fr,16), bi = rl(fi,16);
        float cr = rl(fr,32), ci = rl(fi,32);
        float dr = rl(fr,48), di = rl(fi,48);
        float abr = ar*br - ai*bi, abi = ar*bi + ai*br;
        float cdr = cr*dr - ci*di, cdi = cr*di + ci*dr;
        PFr = abr*cdr - abi*cdi;
        PFi = abr*cdi + abi*cdr;
    }
    // qubit-0 quantities via readlane
    float DA0 = rl(DA,0), DB0 = rl(DB,0), Kr0 = rl(Kr,0), Ki0 = rl(Ki,0);
    float cc0 = rl(cj,0), sc0 = rl(sj,0);
    float meas0 = 0.5f*(1.f+cc0)*DA0*PA + 0.5f*(1.f-cc0)*DB0*PB
                + sc0*(Kr0*PFr - Ki0*PFi);
    float measj = g0 ? meas0 : fmaf(cc0, uu, vv);
    // gather meas vector via readlane (wave-uniform SGPR values)
    float m0 = meas0;
    float m1 = rl(measj,  8), m2 = rl(measj, 16), m3 = rl(measj, 24);
    float m4 = rl(measj, 32), m5 = rl(measj, 40), m6 = rl(measj, 48);
    float m7 = rl(measj, 56);

    // ---- phase C: y = meas @ W_out^T + b_out, LayerNorm, store ----
    // lane owns quads q = 64t + lane (t = 0..2): cols 4q .. 4q+3
    float yv[12];
    float sum = 0.f, sq = 0.f;
    #pragma unroll
    for (int t = 0; t < 3; ++t) {
        const int q4 = (t << 6) + lane;
        float4 bo = LD4<BF>(b_out_, q4);
        float bos[4] = {bo.x, bo.y, bo.z, bo.w};
        #pragma unroll
        for (int e = 0; e < 4; ++e) {
            int c = 4*q4 + e;
            float4 w0 = LD4<BF>(W_out_, c*2);
            float4 w1 = LD4<BF>(W_out_, c*2 + 1);
            float y = bos[e];
            y = fmaf(m0, w0.x, y); y = fmaf(m1, w0.y, y);
            y = fmaf(m2, w0.z, y); y = fmaf(m3, w0.w, y);
            y = fmaf(m4, w1.x, y); y = fmaf(m5, w1.y, y);
            y = fmaf(m6, w1.z, y); y = fmaf(m7, w1.w, y);
            yv[4*t+e] = y;
            sum += y;
            sq = fmaf(y, y, sq);
        }
    }
    // LN reduce: all-VALU butterfly to row-uniform, then 4 readlanes
    sum += dpp_mov<0xB1>(sum);   sq += dpp_mov<0xB1>(sq);
    sum += dpp_mov<0x4E>(sum);   sq += dpp_mov<0x4E>(sq);
    sum += dpp_mov<0x141>(sum);  sq += dpp_mov<0x141>(sq);
    sum += dpp_mov<0x140>(sum);  sq += dpp_mov<0x140>(sq);
    float tsum = (rl(sum,0) + rl(sum,16)) + (rl(sum,32) + rl(sum,48));
    float tsq  = (rl(sq, 0) + rl(sq, 16)) + (rl(sq, 32) + rl(sq, 48));
    float mean = tsum * (1.f/HID);
    float var  = fmaf(tsq, 1.f/HID, -mean*mean);
    float rstd = rsqrtf(var + 1e-5f);
    #pragma unroll
    for (int t = 0; t < 3; ++t) {
        const int q4 = (t << 6) + lane;
        float4 ga = LD4<BF>(gamma_, q4);
        float4 be = LD4<BF>(beta_,  q4);
        float4 o;
        o.x = fmaf((yv[4*t+0]-mean)*rstd, ga.x, be.x);
        o.y = fmaf((yv[4*t+1]-mean)*rstd, ga.y, be.y);
        o.z = fmaf((yv[4*t+2]-mean)*rstd, ga.z, be.z);
        o.w = fmaf((yv[4*t+3]-mean)*rstd, ga.w, be.w);
        ST4<BF>(out_, hb + q4, o);
    }
}

__global__ __launch_bounds__(TPB, 4) void main_kernel(
    const void* hidden_, const void* W_in_, const void* b_in_,
    const void* W_out_, const void* b_out_, const void* wry_, const void* wrz_,
    const void* gamma_, const void* beta_, void* out_)
{
    // dtype sniff: one ballot over the first 64 words of `hidden`
    const int lane = threadIdx.x & 63;
    unsigned wrd = ((const unsigned*)hidden_)[lane];
    unsigned lo  = wrd & 0xffffu;
    unsigned e   = (lo >> 7) & 0xffu;
    bool v = (lo == 0u) || (e >= 100u && e <= 133u);
    unsigned long long mask = __ballot(v);
    int flag = (__popcll(mask) > 32) ? 1 : 0;
    if (flag)
        run_all<1>(hidden_, W_in_, b_in_, W_out_, b_out_, wry_, wrz_,
                   gamma_, beta_, out_);
    else
        run_all<0>(hidden_, W_in_, b_in_, W_out_, b_out_, wry_, wrz_,
                   gamma_, beta_, out_);
}

extern "C" void kernel_launch(void* const* d_in, const int* in_sizes, int n_in,
                              void* d_out, int out_size, void* d_ws, size_t ws_size,
                              hipStream_t stream) {
    const void* hidden = d_in[0];
    const void* W_in   = d_in[1];
    const void* b_in   = d_in[2];
    const void* W_out  = d_in[3];
    const void* b_out  = d_in[4];
    const void* wry    = d_in[5];
    const void* wrz    = d_in[6];
    const void* gamma  = d_in[7];
    const void* beta   = d_in[8];
    (void)d_ws; (void)ws_size;
    main_kernel<<<NBLK, TPB, 0, stream>>>(hidden, W_in, b_in, W_out, b_out,
                                          wry, wrz, gamma, beta, d_out);
}

// Round 7
// 101.906 us; speedup vs baseline: 1.2082x; 1.2082x over previous
//
#include <hip/hip_runtime.h>
#include <hip/hip_bf16.h>

#define NQ    8
#define HID   768
#define BATCH 8192
#define TPB   512                    // 8 waves/block, 1 sample per wave
#define SPB   8
#define NBLK  (BATCH / SPB)          // 1024

// ---------- dtype-generic load/store ----------
template<int BF> __device__ __forceinline__ float LDV(const void* p, int i) {
    if constexpr (BF) return __bfloat162float(((const __hip_bfloat16*)p)[i]);
    else return ((const float*)p)[i];
}
template<int BF> __device__ __forceinline__ void STV(void* p, int i, float v) {
    if constexpr (BF) ((__hip_bfloat16*)p)[i] = __float2bfloat16(v);
    else ((float*)p)[i] = v;
}
template<int BF> __device__ __forceinline__ float4 LD4(const void* p, int i4) {
    if constexpr (BF) {
        ushort4 v = ((const ushort4*)p)[i4];
        float4 r;
        r.x = __uint_as_float(((unsigned)v.x) << 16);
        r.y = __uint_as_float(((unsigned)v.y) << 16);
        r.z = __uint_as_float(((unsigned)v.z) << 16);
        r.w = __uint_as_float(((unsigned)v.w) << 16);
        return r;
    } else {
        return ((const float4*)p)[i4];
    }
}

// ---------- fused kernel: weights in LDS (conflict-free), 1 wave = 1 sample --
template<int BF>
__device__ __forceinline__ void run_all(
    const void* hidden_, const void* W_in_, const void* b_in_,
    const void* W_out_, const void* b_out_, const void* wry_, const void* wrz_,
    const void* gamma_, const void* beta_, void* out_,
    float* sWin, float4* sWoutLo, float4* sWoutHi)
{
    const int tid  = threadIdx.x;
    const int lane = tid & 63;
    const int wv   = tid >> 6;
    const int j    = lane >> 3;       // qubit group for circuit phase
    const int b    = blockIdx.x * SPB + wv;

    // ---- stage weights to LDS (once per block, fp32) ----
    #pragma unroll
    for (int k = 0; k < (NQ*HID/4)/TPB; ++k) {      // 1536 float4 of W_in
        int idx = tid + k*TPB;
        ((float4*)sWin)[idx] = LD4<BF>(W_in_, idx); // [j][c] row-major, matches input
    }
    #pragma unroll
    for (int k = 0; k < HID/TPB + 1; ++k) {         // 768 cols of W_out
        int c = tid + k*TPB;
        if (c < HID) {
            sWoutLo[c] = LD4<BF>(W_out_, c*2);      // W_out[c][0..3]
            sWoutHi[c] = LD4<BF>(W_out_, c*2 + 1);  // W_out[c][4..7]
        }
    }
    __syncthreads();

    // ---- per-lane circuit constants for qubit j (branch-free) ----
    float DA, DB, Kr, Ki;
    {
        float ry0 = LDV<BF>(wry_, j), ry1 = LDV<BF>(wry_, NQ + j);
        float rz0 = LDV<BF>(wrz_, j), rz1 = LDV<BF>(wrz_, NQ + j);
        float cA = cosf(0.5f*ry0), sA = sinf(0.5f*ry0);
        float cB = cosf(0.5f*ry1), sB = sinf(0.5f*ry1);
        float p0c = cosf(0.5f*rz0), p0s = sinf(0.5f*rz0);
        float p1c = cosf(0.5f*rz1), p1s = sinf(0.5f*rz1);
        float g00r =  cA*p0c, g00i = -cA*p0s;
        float g01r = -sA*p0c, g01i =  sA*p0s;
        float g10r =  sA*p0c, g10i =  sA*p0s;
        float g11r =  cA*p0c, g11i =  cA*p0s;
        float h00r = cB*g00r - sB*g10r, h00i = cB*g00i - sB*g10i;
        float h01r = cB*g01r - sB*g11r, h01i = cB*g01i - sB*g11i;
        float h10r = sB*g00r + cB*g10r, h10i = sB*g00i + cB*g10i;
        float h11r = sB*g01r + cB*g11r, h11i = sB*g01i + cB*g11i;
        float f00r = h00r*p1c + h00i*p1s, f00i = h00i*p1c - h00r*p1s;
        float f01r = h01r*p1c + h01i*p1s, f01i = h01i*p1c - h01r*p1s;
        float f10r = h10r*p1c - h10i*p1s, f10i = h10i*p1c + h10r*p1s;
        float f11r = h11r*p1c - h11i*p1s, f11i = h11i*p1c + h11r*p1s;
        DA = f00r*f00r + f00i*f00i - (f10r*f10r + f10i*f10i);
        DB = f01r*f01r + f01i*f01i - (f11r*f11r + f11i*f11i);
        Kr = (f00r*f01r + f00i*f01i) - (f10r*f11r + f10i*f11i);
        Ki = (f00i*f01r - f00r*f01i) - (f10i*f11r - f10r*f11i);
    }

    // ---- phase A: partial dots for all 8 qubits; hidden non-redundant ----
    // lane owns quads q4 = lane + 64t (t=0..2); W_in from LDS (bank 4*lane%32,
    // conflict-free per instruction since jj is fixed across lanes).
    float p[NQ];
    #pragma unroll
    for (int q = 0; q < NQ; ++q) p[q] = 0.f;
    const int hb = b * (HID/4);
    #pragma unroll
    for (int t = 0; t < 3; ++t) {
        const int q4 = (t << 6) + lane;
        float4 h = LD4<BF>(hidden_, hb + q4);
        #pragma unroll
        for (int jj = 0; jj < NQ; ++jj) {
            float4 w = ((const float4*)(sWin + jj*HID))[q4];
            p[jj] = fmaf(h.x, w.x, p[jj]);
            p[jj] = fmaf(h.y, w.y, p[jj]);
            p[jj] = fmaf(h.z, w.z, p[jj]);
            p[jj] = fmaf(h.w, w.w, p[jj]);
        }
    }
    // ---- multi-value butterfly: land z_j in lanes with group==j (R3) ----
    const bool mb0 = ((lane >> 3) & 1) != 0;
    const bool mb1 = ((lane >> 4) & 1) != 0;
    const bool mb2 = ((lane >> 5) & 1) != 0;
    float np[4];
    #pragma unroll
    for (int k = 0; k < 4; ++k) {
        float sent = mb0 ? p[2*k]   : p[2*k+1];
        float keep = mb0 ? p[2*k+1] : p[2*k];
        np[k] = keep + __shfl_xor(sent, 8, 64);
    }
    float nq2[2];
    #pragma unroll
    for (int k = 0; k < 2; ++k) {
        float sent = mb1 ? np[2*k]   : np[2*k+1];
        float keep = mb1 ? np[2*k+1] : np[2*k];
        nq2[k] = keep + __shfl_xor(sent, 16, 64);
    }
    float z;
    {
        float sent = mb2 ? nq2[0] : nq2[1];
        float keep = mb2 ? nq2[1] : nq2[0];
        z = keep + __shfl_xor(sent, 32, 64);
    }
    z += __shfl_xor(z, 1, 64);
    z += __shfl_xor(z, 2, 64);
    z += __shfl_xor(z, 4, 64);

    // ---- circuit: one tanh/sinpi/cospi per lane (R3 verbatim) ----
    float zb = z + LDV<BF>(b_in_, j);
    float th = tanhf(zb);
    float sj = sinpif(th), cj = cospif(th);

    float ca = 0.5f * (DA + DB), da = 0.5f * (DA - DB);
    const bool g0 = (j == 0);
    float uu = da * cj;
    float vv = fmaf(Kr, sj, ca);
    float MA = g0 ? 1.f : (vv + uu), MB = g0 ? 1.f : (vv - uu);
    float fr = g0 ? 1.f : Kr,        fi = g0 ? 0.f : (cj * Ki);
    #pragma unroll
    for (int d = 8; d < 64; d <<= 1) {
        MA *= __shfl_xor(MA, d, 64);
        MB *= __shfl_xor(MB, d, 64);
        float qr = __shfl_xor(fr, d, 64);
        float qi = __shfl_xor(fi, d, 64);
        float nr = fr*qr - fi*qi;
        float ni = fr*qi + fi*qr;
        fr = nr; fi = ni;
    }
    float DA0 = __shfl(DA, 0, 64), DB0 = __shfl(DB, 0, 64);
    float Kr0 = __shfl(Kr, 0, 64), Ki0 = __shfl(Ki, 0, 64);
    float cc0 = __shfl(cj, 0, 64), sc0 = __shfl(sj, 0, 64);
    float meas0 = 0.5f*(1.f+cc0)*DA0*MA + 0.5f*(1.f-cc0)*DB0*MB
                + sc0*(Kr0*fr - Ki0*fi);
    float measj = g0 ? meas0 : fmaf(cc0, uu, vv);
    float m0 = meas0;
    float m1 = __shfl(measj,  8, 64), m2 = __shfl(measj, 16, 64);
    float m3 = __shfl(measj, 24, 64), m4 = __shfl(measj, 32, 64);
    float m5 = __shfl(measj, 40, 64), m6 = __shfl(measj, 48, 64);
    float m7 = __shfl(measj, 56, 64);

    // ---- phase C: lane owns cols c = lane + 64k (k=0..11) ----
    // W_out from LDS (float4 idx ≡ lane mod 8 -> conflict-free);
    // b_out/gamma/beta/out scalar, 256B-coalesced per instruction.
    const int rowbase = b * HID;
    float yv[12];
    float sum = 0.f, sq = 0.f;
    #pragma unroll
    for (int k = 0; k < 12; ++k) {
        const int c = lane + (k << 6);
        float4 w0 = sWoutLo[c];
        float4 w1 = sWoutHi[c];
        float y = LDV<BF>(b_out_, c);
        y = fmaf(m0, w0.x, y); y = fmaf(m1, w0.y, y);
        y = fmaf(m2, w0.z, y); y = fmaf(m3, w0.w, y);
        y = fmaf(m4, w1.x, y); y = fmaf(m5, w1.y, y);
        y = fmaf(m6, w1.z, y); y = fmaf(m7, w1.w, y);
        yv[k] = y;
        sum += y;
        sq = fmaf(y, y, sq);
    }
    #pragma unroll
    for (int d = 1; d < 64; d <<= 1) {
        sum += __shfl_xor(sum, d, 64);
        sq  += __shfl_xor(sq,  d, 64);
    }
    float mean = sum * (1.f/HID);
    float var  = fmaf(sq, 1.f/HID, -mean*mean);
    float rstd = rsqrtf(var + 1e-5f);
    #pragma unroll
    for (int k = 0; k < 12; ++k) {
        const int c = lane + (k << 6);
        float g  = LDV<BF>(gamma_, c);
        float be = LDV<BF>(beta_,  c);
        float o  = fmaf((yv[k] - mean) * rstd, g, be);
        STV<BF>(out_, rowbase + c, o);
    }
}

__global__ __launch_bounds__(TPB, 2) void main_kernel(
    const void* hidden_, const void* W_in_, const void* b_in_,
    const void* W_out_, const void* b_out_, const void* wry_, const void* wrz_,
    const void* gamma_, const void* beta_, void* out_)
{
    __shared__ __align__(16) float  sWin[NQ*HID];     // 24 KB, [j][c]
    __shared__ __align__(16) float4 sWoutLo[HID];     // 12 KB, W_out[c][0..3]
    __shared__ __align__(16) float4 sWoutHi[HID];     // 12 KB, W_out[c][4..7]
    // dtype sniff: one ballot over the first 64 words of `hidden`
    const int lane = threadIdx.x & 63;
    unsigned wrd = ((const unsigned*)hidden_)[lane];
    unsigned lo  = wrd & 0xffffu;
    unsigned e   = (lo >> 7) & 0xffu;
    bool v = (lo == 0u) || (e >= 100u && e <= 133u);
    unsigned long long mask = __ballot(v);
    int flag = (__popcll(mask) > 32) ? 1 : 0;
    if (flag)
        run_all<1>(hidden_, W_in_, b_in_, W_out_, b_out_, wry_, wrz_,
                   gamma_, beta_, out_, sWin, sWoutLo, sWoutHi);
    else
        run_all<0>(hidden_, W_in_, b_in_, W_out_, b_out_, wry_, wrz_,
                   gamma_, beta_, out_, sWin, sWoutLo, sWoutHi);
}

extern "C" void kernel_launch(void* const* d_in, const int* in_sizes, int n_in,
                              void* d_out, int out_size, void* d_ws, size_t ws_size,
                              hipStream_t stream) {
    const void* hidden = d_in[0];
    const void* W_in   = d_in[1];
    const void* b_in   = d_in[2];
    const void* W_out  = d_in[3];
    const void* b_out  = d_in[4];
    const void* wry    = d_in[5];
    const void* wrz    = d_in[6];
    const void* gamma  = d_in[7];
    const void* beta   = d_in[8];
    (void)d_ws; (void)ws_size;
    main_kernel<<<NBLK, TPB, 0, stream>>>(hidden, W_in, b_in, W_out, b_out,
                                          wry, wrz, gamma, beta, d_out);
}

// Round 8
// 99.441 us; speedup vs baseline: 1.2381x; 1.0248x over previous
//
#include <hip/hip_runtime.h>
#include <hip/hip_bf16.h>

#define NQ    8
#define HID   768
#define BATCH 8192
#define TPB   1024                   // 16 waves/block, 1 sample per wave
#define SPB   16
#define NBLK  (BATCH / SPB)          // 512 blocks = 2/CU = single generation

// ---------- dtype-generic load/store ----------
template<int BF> __device__ __forceinline__ float LDV(const void* p, int i) {
    if constexpr (BF) return __bfloat162float(((const __hip_bfloat16*)p)[i]);
    else return ((const float*)p)[i];
}
template<int BF> __device__ __forceinline__ void STV(void* p, int i, float v) {
    if constexpr (BF) ((__hip_bfloat16*)p)[i] = __float2bfloat16(v);
    else ((float*)p)[i] = v;
}
template<int BF> __device__ __forceinline__ float4 LD4(const void* p, int i4) {
    if constexpr (BF) {
        ushort4 v = ((const ushort4*)p)[i4];
        float4 r;
        r.x = __uint_as_float(((unsigned)v.x) << 16);
        r.y = __uint_as_float(((unsigned)v.y) << 16);
        r.z = __uint_as_float(((unsigned)v.z) << 16);
        r.w = __uint_as_float(((unsigned)v.w) << 16);
        return r;
    } else {
        return ((const float4*)p)[i4];
    }
}

// ---------- fused kernel: ALL params in LDS, 32 waves/CU, one generation ----
template<int BF>
__device__ __forceinline__ void run_all(
    const void* hidden_, const void* W_in_, const void* b_in_,
    const void* W_out_, const void* b_out_, const void* wry_, const void* wrz_,
    const void* gamma_, const void* beta_, void* out_,
    float* sWin, float4* sWoutLo, float4* sWoutHi,
    float* sBout, float2* sGB)
{
    const int tid  = threadIdx.x;
    const int lane = tid & 63;
    const int wv   = tid >> 6;
    const int j    = lane >> 3;       // qubit group for circuit phase
    const int b    = blockIdx.x * SPB + wv;

    // ---- stage everything to LDS (once per 16 samples, fp32) ----
    ((float4*)sWin)[tid] = LD4<BF>(W_in_, tid);          // 1536 float4 total
    if (tid < NQ*HID/4 - TPB)
        ((float4*)sWin)[tid + TPB] = LD4<BF>(W_in_, tid + TPB);
    if (tid < HID) {
        sWoutLo[tid] = LD4<BF>(W_out_, tid*2);           // W_out[c][0..3]
        sWoutHi[tid] = LD4<BF>(W_out_, tid*2 + 1);       // W_out[c][4..7]
        sBout[tid]   = LDV<BF>(b_out_, tid);
        float g  = LDV<BF>(gamma_, tid);
        float be = LDV<BF>(beta_,  tid);
        sGB[tid] = make_float2(g, be);
    }

    // ---- per-lane circuit constants for qubit j (overlaps staging) ----
    float DA, DB, Kr, Ki;
    {
        float ry0 = LDV<BF>(wry_, j), ry1 = LDV<BF>(wry_, NQ + j);
        float rz0 = LDV<BF>(wrz_, j), rz1 = LDV<BF>(wrz_, NQ + j);
        float cA = cosf(0.5f*ry0), sA = sinf(0.5f*ry0);
        float cB = cosf(0.5f*ry1), sB = sinf(0.5f*ry1);
        float p0c = cosf(0.5f*rz0), p0s = sinf(0.5f*rz0);
        float p1c = cosf(0.5f*rz1), p1s = sinf(0.5f*rz1);
        float g00r =  cA*p0c, g00i = -cA*p0s;
        float g01r = -sA*p0c, g01i =  sA*p0s;
        float g10r =  sA*p0c, g10i =  sA*p0s;
        float g11r =  cA*p0c, g11i =  cA*p0s;
        float h00r = cB*g00r - sB*g10r, h00i = cB*g00i - sB*g10i;
        float h01r = cB*g01r - sB*g11r, h01i = cB*g01i - sB*g11i;
        float h10r = sB*g00r + cB*g10r, h10i = sB*g00i + cB*g10i;
        float h11r = sB*g01r + cB*g11r, h11i = sB*g01i + cB*g11i;
        float f00r = h00r*p1c + h00i*p1s, f00i = h00i*p1c - h00r*p1s;
        float f01r = h01r*p1c + h01i*p1s, f01i = h01i*p1c - h01r*p1s;
        float f10r = h10r*p1c - h10i*p1s, f10i = h10i*p1c + h10r*p1s;
        float f11r = h11r*p1c - h11i*p1s, f11i = h11i*p1c + h11r*p1s;
        DA = f00r*f00r + f00i*f00i - (f10r*f10r + f10i*f10i);
        DB = f01r*f01r + f01i*f01i - (f11r*f11r + f11i*f11i);
        Kr = (f00r*f01r + f00i*f01i) - (f10r*f11r + f10i*f11i);
        Ki = (f00i*f01r - f00r*f01i) - (f10i*f11r - f10r*f11i);
    }
    __syncthreads();

    // ---- phase A: partial dots for all 8 qubits; hidden non-redundant ----
    // lane owns quads q4 = lane + 64t (t=0..2); sWin reads lane-contiguous.
    float p[NQ];
    #pragma unroll
    for (int q = 0; q < NQ; ++q) p[q] = 0.f;
    const int hb = b * (HID/4);
    #pragma unroll
    for (int t = 0; t < 3; ++t) {
        const int q4 = (t << 6) + lane;
        float4 h = LD4<BF>(hidden_, hb + q4);
        #pragma unroll
        for (int jj = 0; jj < NQ; ++jj) {
            float4 w = ((const float4*)(sWin + jj*HID))[q4];
            p[jj] = fmaf(h.x, w.x, p[jj]);
            p[jj] = fmaf(h.y, w.y, p[jj]);
            p[jj] = fmaf(h.z, w.z, p[jj]);
            p[jj] = fmaf(h.w, w.w, p[jj]);
        }
    }
    // ---- multi-value butterfly: land z_j in lanes with group==j ----
    const bool mb0 = ((lane >> 3) & 1) != 0;
    const bool mb1 = ((lane >> 4) & 1) != 0;
    const bool mb2 = ((lane >> 5) & 1) != 0;
    float np[4];
    #pragma unroll
    for (int k = 0; k < 4; ++k) {
        float sent = mb0 ? p[2*k]   : p[2*k+1];
        float keep = mb0 ? p[2*k+1] : p[2*k];
        np[k] = keep + __shfl_xor(sent, 8, 64);
    }
    float nq2[2];
    #pragma unroll
    for (int k = 0; k < 2; ++k) {
        float sent = mb1 ? np[2*k]   : np[2*k+1];
        float keep = mb1 ? np[2*k+1] : np[2*k];
        nq2[k] = keep + __shfl_xor(sent, 16, 64);
    }
    float z;
    {
        float sent = mb2 ? nq2[0] : nq2[1];
        float keep = mb2 ? nq2[1] : nq2[0];
        z = keep + __shfl_xor(sent, 32, 64);
    }
    z += __shfl_xor(z, 1, 64);
    z += __shfl_xor(z, 2, 64);
    z += __shfl_xor(z, 4, 64);

    // ---- circuit: one tanh/sinpi/cospi per lane ----
    float zb = z + LDV<BF>(b_in_, j);
    float th = tanhf(zb);
    float sj = sinpif(th), cj = cospif(th);

    float ca = 0.5f * (DA + DB), da = 0.5f * (DA - DB);
    const bool g0 = (j == 0);
    float uu = da * cj;
    float vv = fmaf(Kr, sj, ca);
    float MA = g0 ? 1.f : (vv + uu), MB = g0 ? 1.f : (vv - uu);
    float fr = g0 ? 1.f : Kr,        fi = g0 ? 0.f : (cj * Ki);
    #pragma unroll
    for (int d = 8; d < 64; d <<= 1) {
        MA *= __shfl_xor(MA, d, 64);
        MB *= __shfl_xor(MB, d, 64);
        float qr = __shfl_xor(fr, d, 64);
        float qi = __shfl_xor(fi, d, 64);
        float nr = fr*qr - fi*qi;
        float ni = fr*qi + fi*qr;
        fr = nr; fi = ni;
    }
    float DA0 = __shfl(DA, 0, 64), DB0 = __shfl(DB, 0, 64);
    float Kr0 = __shfl(Kr, 0, 64), Ki0 = __shfl(Ki, 0, 64);
    float cc0 = __shfl(cj, 0, 64), sc0 = __shfl(sj, 0, 64);
    float meas0 = 0.5f*(1.f+cc0)*DA0*MA + 0.5f*(1.f-cc0)*DB0*MB
                + sc0*(Kr0*fr - Ki0*fi);
    float measj = g0 ? meas0 : fmaf(cc0, uu, vv);
    float m0 = meas0;
    float m1 = __shfl(measj,  8, 64), m2 = __shfl(measj, 16, 64);
    float m3 = __shfl(measj, 24, 64), m4 = __shfl(measj, 32, 64);
    float m5 = __shfl(measj, 40, 64), m6 = __shfl(measj, 48, 64);
    float m7 = __shfl(measj, 56, 64);

    // ---- phase C: lane owns cols c = lane + 64k (k=0..11), all LDS reads ----
    const int rowbase = b * HID;
    float yv[12];
    float sum = 0.f, sq = 0.f;
    #pragma unroll
    for (int k = 0; k < 12; ++k) {
        const int c = lane + (k << 6);
        float4 w0 = sWoutLo[c];
        float4 w1 = sWoutHi[c];
        float y = sBout[c];
        y = fmaf(m0, w0.x, y); y = fmaf(m1, w0.y, y);
        y = fmaf(m2, w0.z, y); y = fmaf(m3, w0.w, y);
        y = fmaf(m4, w1.x, y); y = fmaf(m5, w1.y, y);
        y = fmaf(m6, w1.z, y); y = fmaf(m7, w1.w, y);
        yv[k] = y;
        sum += y;
        sq = fmaf(y, y, sq);
    }
    #pragma unroll
    for (int d = 1; d < 64; d <<= 1) {
        sum += __shfl_xor(sum, d, 64);
        sq  += __shfl_xor(sq,  d, 64);
    }
    float mean = sum * (1.f/HID);
    float var  = fmaf(sq, 1.f/HID, -mean*mean);
    float rstd = rsqrtf(var + 1e-5f);
    #pragma unroll
    for (int k = 0; k < 12; ++k) {
        const int c = lane + (k << 6);
        float2 gb = sGB[c];
        float o = fmaf((yv[k] - mean) * rstd, gb.x, gb.y);
        STV<BF>(out_, rowbase + c, o);
    }
}

__global__ __launch_bounds__(TPB, 8) void main_kernel(
    const void* hidden_, const void* W_in_, const void* b_in_,
    const void* W_out_, const void* b_out_, const void* wry_, const void* wrz_,
    const void* gamma_, const void* beta_, void* out_)
{
    __shared__ __align__(16) float  sWin[NQ*HID];     // 24 KB, [j][c]
    __shared__ __align__(16) float4 sWoutLo[HID];     // 12 KB
    __shared__ __align__(16) float4 sWoutHi[HID];     // 12 KB
    __shared__ __align__(16) float  sBout[HID];       //  3 KB
    __shared__ __align__(16) float2 sGB[HID];         //  6 KB   (57 KB total)
    // dtype sniff: one ballot over the first 64 words of `hidden`
    const int lane = threadIdx.x & 63;
    unsigned wrd = ((const unsigned*)hidden_)[lane];
    unsigned lo  = wrd & 0xffffu;
    unsigned e   = (lo >> 7) & 0xffu;
    bool v = (lo == 0u) || (e >= 100u && e <= 133u);
    unsigned long long mask = __ballot(v);
    int flag = (__popcll(mask) > 32) ? 1 : 0;
    if (flag)
        run_all<1>(hidden_, W_in_, b_in_, W_out_, b_out_, wry_, wrz_,
                   gamma_, beta_, out_, sWin, sWoutLo, sWoutHi, sBout, sGB);
    else
        run_all<0>(hidden_, W_in_, b_in_, W_out_, b_out_, wry_, wrz_,
                   gamma_, beta_, out_, sWin, sWoutLo, sWoutHi, sBout, sGB);
}

extern "C" void kernel_launch(void* const* d_in, const int* in_sizes, int n_in,
                              void* d_out, int out_size, void* d_ws, size_t ws_size,
                              hipStream_t stream) {
    const void* hidden = d_in[0];
    const void* W_in   = d_in[1];
    const void* b_in   = d_in[2];
    const void* W_out  = d_in[3];
    const void* b_out  = d_in[4];
    const void* wry    = d_in[5];
    const void* wrz    = d_in[6];
    const void* gamma  = d_in[7];
    const void* beta   = d_in[8];
    (void)d_ws; (void)ws_size;
    main_kernel<<<NBLK, TPB, 0, stream>>>(hidden, W_in, b_in, W_out, b_out,
                                          wry, wrz, gamma, beta, d_out);
}

// Round 9
// 98.156 us; speedup vs baseline: 1.2544x; 1.0131x over previous
//
#include <hip/hip_runtime.h>
#include <hip/hip_bf16.h>

#define NQ    8
#define HID   768
#define BATCH 8192
#define TPB   1024                   // 16 waves/block, 1 sample per wave
#define SPB   16
#define NBLK  (BATCH / SPB)          // 512 blocks = 2/CU = single generation

// ---------- dtype-generic load/store ----------
template<int BF> __device__ __forceinline__ float LDV(const void* p, int i) {
    if constexpr (BF) return __bfloat162float(((const __hip_bfloat16*)p)[i]);
    else return ((const float*)p)[i];
}
template<int BF> __device__ __forceinline__ void STV(void* p, int i, float v) {
    if constexpr (BF) ((__hip_bfloat16*)p)[i] = __float2bfloat16(v);
    else ((float*)p)[i] = v;
}
template<int BF> __device__ __forceinline__ float4 LD4(const void* p, int i4) {
    if constexpr (BF) {
        ushort4 v = ((const ushort4*)p)[i4];
        float4 r;
        r.x = __uint_as_float(((unsigned)v.x) << 16);
        r.y = __uint_as_float(((unsigned)v.y) << 16);
        r.z = __uint_as_float(((unsigned)v.z) << 16);
        r.w = __uint_as_float(((unsigned)v.w) << 16);
        return r;
    } else {
        return ((const float4*)p)[i4];
    }
}
__device__ __forceinline__ float bflo(unsigned w) { return __uint_as_float(w << 16); }
__device__ __forceinline__ float bfhi(unsigned w) { return __uint_as_float(w & 0xffff0000u); }

// LDS layout (carved from one char buffer):
//  BF=1: sWinU  bf16[8][768]   @0      (12288 B)
//        sWoutU uint4[768]     @12288  (12288 B)  row c = W_out[c][0..7] bf16
//        sBout  float[768]     @24576  ( 3072 B)
//        sGB    float2[768]    @27648  ( 6144 B)
//  BF=0: sWin   float[8][768]  @0      (24576 B)
//        sWoutLo float4[768]   @24576  (12288 B)
//        sWoutHi float4[768]   @36864  (12288 B)
//        sBout  float[768]     @49152  ( 3072 B)
//        sGB    float2[768]    @52224  ( 6144 B)
#define SMEM_BYTES 58368

template<int BF>
__device__ __forceinline__ void run_all(
    const void* hidden_, const void* W_in_, const void* b_in_,
    const void* W_out_, const void* b_out_, const void* wry_, const void* wrz_,
    const void* gamma_, const void* beta_, void* out_, char* smem)
{
    const int tid  = threadIdx.x;
    const int lane = tid & 63;
    const int wv   = tid >> 6;
    const int j    = lane >> 3;       // qubit group for circuit phase
    const int b    = blockIdx.x * SPB + wv;

    float* sBout;
    float2* sGB;
    if constexpr (BF) {
        sBout = (float*)(smem + 24576);
        sGB   = (float2*)(smem + 27648);
        // raw bf16 copies: W_in 768 uint4, W_out rows are exactly uint4
        if (tid < 768) {
            ((uint4*)smem)[tid]           = ((const uint4*)W_in_)[tid];
            ((uint4*)(smem + 12288))[tid] = ((const uint4*)W_out_)[tid];
            sBout[tid] = LDV<BF>(b_out_, tid);
            sGB[tid]   = make_float2(LDV<BF>(gamma_, tid), LDV<BF>(beta_, tid));
        }
    } else {
        sBout = (float*)(smem + 49152);
        sGB   = (float2*)(smem + 52224);
        float* sWin = (float*)smem;
        float4* sWoutLo = (float4*)(smem + 24576);
        float4* sWoutHi = (float4*)(smem + 36864);
        ((float4*)sWin)[tid] = LD4<BF>(W_in_, tid);
        if (tid < NQ*HID/4 - TPB)
            ((float4*)sWin)[tid + TPB] = LD4<BF>(W_in_, tid + TPB);
        if (tid < HID) {
            sWoutLo[tid] = LD4<BF>(W_out_, tid*2);
            sWoutHi[tid] = LD4<BF>(W_out_, tid*2 + 1);
            sBout[tid]   = LDV<BF>(b_out_, tid);
            sGB[tid]     = make_float2(LDV<BF>(gamma_, tid), LDV<BF>(beta_, tid));
        }
    }

    // ---- per-lane circuit constants for qubit j (overlaps staging loads) ----
    float DA, DB, Kr, Ki;
    {
        float ry0 = LDV<BF>(wry_, j), ry1 = LDV<BF>(wry_, NQ + j);
        float rz0 = LDV<BF>(wrz_, j), rz1 = LDV<BF>(wrz_, NQ + j);
        float cA = cosf(0.5f*ry0), sA = sinf(0.5f*ry0);
        float cB = cosf(0.5f*ry1), sB = sinf(0.5f*ry1);
        float p0c = cosf(0.5f*rz0), p0s = sinf(0.5f*rz0);
        float p1c = cosf(0.5f*rz1), p1s = sinf(0.5f*rz1);
        float g00r =  cA*p0c, g00i = -cA*p0s;
        float g01r = -sA*p0c, g01i =  sA*p0s;
        float g10r =  sA*p0c, g10i =  sA*p0s;
        float g11r =  cA*p0c, g11i =  cA*p0s;
        float h00r = cB*g00r - sB*g10r, h00i = cB*g00i - sB*g10i;
        float h01r = cB*g01r - sB*g11r, h01i = cB*g01i - sB*g11i;
        float h10r = sB*g00r + cB*g10r, h10i = sB*g00i + cB*g10i;
        float h11r = sB*g01r + cB*g11r, h11i = sB*g01i + cB*g11i;
        float f00r = h00r*p1c + h00i*p1s, f00i = h00i*p1c - h00r*p1s;
        float f01r = h01r*p1c + h01i*p1s, f01i = h01i*p1c - h01r*p1s;
        float f10r = h10r*p1c - h10i*p1s, f10i = h10i*p1c + h10r*p1s;
        float f11r = h11r*p1c - h11i*p1s, f11i = h11i*p1c + h11r*p1s;
        DA = f00r*f00r + f00i*f00i - (f10r*f10r + f10i*f10i);
        DB = f01r*f01r + f01i*f01i - (f11r*f11r + f11i*f11i);
        Kr = (f00r*f01r + f00i*f01i) - (f10r*f11r + f10i*f11i);
        Ki = (f00i*f01r - f00r*f01i) - (f10i*f11r - f10r*f11i);
    }
    __syncthreads();

    // ---- phase A: partial dots for all 8 qubits; hidden non-redundant ----
    float p[NQ];
    #pragma unroll
    for (int q = 0; q < NQ; ++q) p[q] = 0.f;
    const int hb = b * (HID/4);
    #pragma unroll
    for (int t = 0; t < 3; ++t) {
        const int q4 = (t << 6) + lane;
        float4 h = LD4<BF>(hidden_, hb + q4);
        if constexpr (BF) {
            const uint2* sWinU2 = (const uint2*)smem;  // [j][q4] 4 bf16 cols
            #pragma unroll
            for (int jj = 0; jj < NQ; ++jj) {
                uint2 w = sWinU2[jj*(HID/4) + q4];
                p[jj] = fmaf(h.x, bflo(w.x), p[jj]);
                p[jj] = fmaf(h.y, bfhi(w.x), p[jj]);
                p[jj] = fmaf(h.z, bflo(w.y), p[jj]);
                p[jj] = fmaf(h.w, bfhi(w.y), p[jj]);
            }
        } else {
            const float* sWin = (const float*)smem;
            #pragma unroll
            for (int jj = 0; jj < NQ; ++jj) {
                float4 w = ((const float4*)(sWin + jj*HID))[q4];
                p[jj] = fmaf(h.x, w.x, p[jj]);
                p[jj] = fmaf(h.y, w.y, p[jj]);
                p[jj] = fmaf(h.z, w.z, p[jj]);
                p[jj] = fmaf(h.w, w.w, p[jj]);
            }
        }
    }
    // ---- multi-value butterfly: land z_j in lanes with group==j ----
    const bool mb0 = ((lane >> 3) & 1) != 0;
    const bool mb1 = ((lane >> 4) & 1) != 0;
    const bool mb2 = ((lane >> 5) & 1) != 0;
    float np[4];
    #pragma unroll
    for (int k = 0; k < 4; ++k) {
        float sent = mb0 ? p[2*k]   : p[2*k+1];
        float keep = mb0 ? p[2*k+1] : p[2*k];
        np[k] = keep + __shfl_xor(sent, 8, 64);
    }
    float nq2[2];
    #pragma unroll
    for (int k = 0; k < 2; ++k) {
        float sent = mb1 ? np[2*k]   : np[2*k+1];
        float keep = mb1 ? np[2*k+1] : np[2*k];
        nq2[k] = keep + __shfl_xor(sent, 16, 64);
    }
    float z;
    {
        float sent = mb2 ? nq2[0] : nq2[1];
        float keep = mb2 ? nq2[1] : nq2[0];
        z = keep + __shfl_xor(sent, 32, 64);
    }
    z += __shfl_xor(z, 1, 64);
    z += __shfl_xor(z, 2, 64);
    z += __shfl_xor(z, 4, 64);

    // ---- circuit: one tanh/sinpi/cospi per lane ----
    float zb = z + LDV<BF>(b_in_, j);
    float th = tanhf(zb);
    float sj = sinpif(th), cj = cospif(th);

    float ca = 0.5f * (DA + DB), da = 0.5f * (DA - DB);
    const bool g0 = (j == 0);
    float uu = da * cj;
    float vv = fmaf(Kr, sj, ca);
    float MA = g0 ? 1.f : (vv + uu), MB = g0 ? 1.f : (vv - uu);
    float fr = g0 ? 1.f : Kr,        fi = g0 ? 0.f : (cj * Ki);
    #pragma unroll
    for (int d = 8; d < 64; d <<= 1) {
        MA *= __shfl_xor(MA, d, 64);
        MB *= __shfl_xor(MB, d, 64);
        float qr = __shfl_xor(fr, d, 64);
        float qi = __shfl_xor(fi, d, 64);
        float nr = fr*qr - fi*qi;
        float ni = fr*qi + fi*qr;
        fr = nr; fi = ni;
    }
    float DA0 = __shfl(DA, 0, 64), DB0 = __shfl(DB, 0, 64);
    float Kr0 = __shfl(Kr, 0, 64), Ki0 = __shfl(Ki, 0, 64);
    float cc0 = __shfl(cj, 0, 64), sc0 = __shfl(sj, 0, 64);
    float meas0 = 0.5f*(1.f+cc0)*DA0*MA + 0.5f*(1.f-cc0)*DB0*MB
                + sc0*(Kr0*fr - Ki0*fi);
    float measj = g0 ? meas0 : fmaf(cc0, uu, vv);
    float m0 = meas0;
    float m1 = __shfl(measj,  8, 64), m2 = __shfl(measj, 16, 64);
    float m3 = __shfl(measj, 24, 64), m4 = __shfl(measj, 32, 64);
    float m5 = __shfl(measj, 40, 64), m6 = __shfl(measj, 48, 64);
    float m7 = __shfl(measj, 56, 64);

    // ---- phase C: lane owns cols c = lane + 64k (k=0..11) ----
    const int rowbase = b * HID;
    float yv[12];
    float sum = 0.f, sq = 0.f;
    #pragma unroll
    for (int k = 0; k < 12; ++k) {
        const int c = lane + (k << 6);
        float y = sBout[c];
        if constexpr (BF) {
            uint4 wp = ((const uint4*)(smem + 12288))[c];  // 8 bf16 coeffs
            y = fmaf(m0, bflo(wp.x), y); y = fmaf(m1, bfhi(wp.x), y);
            y = fmaf(m2, bflo(wp.y), y); y = fmaf(m3, bfhi(wp.y), y);
            y = fmaf(m4, bflo(wp.z), y); y = fmaf(m5, bfhi(wp.z), y);
            y = fmaf(m6, bflo(wp.w), y); y = fmaf(m7, bfhi(wp.w), y);
        } else {
            float4 w0 = ((const float4*)(smem + 24576))[c];
            float4 w1 = ((const float4*)(smem + 36864))[c];
            y = fmaf(m0, w0.x, y); y = fmaf(m1, w0.y, y);
            y = fmaf(m2, w0.z, y); y = fmaf(m3, w0.w, y);
            y = fmaf(m4, w1.x, y); y = fmaf(m5, w1.y, y);
            y = fmaf(m6, w1.z, y); y = fmaf(m7, w1.w, y);
        }
        yv[k] = y;
        sum += y;
        sq = fmaf(y, y, sq);
    }
    #pragma unroll
    for (int d = 1; d < 64; d <<= 1) {
        sum += __shfl_xor(sum, d, 64);
        sq  += __shfl_xor(sq,  d, 64);
    }
    float mean = sum * (1.f/HID);
    float var  = fmaf(sq, 1.f/HID, -mean*mean);
    float rstd = rsqrtf(var + 1e-5f);
    #pragma unroll
    for (int k = 0; k < 12; ++k) {
        const int c = lane + (k << 6);
        float2 gb = sGB[c];
        float o = fmaf((yv[k] - mean) * rstd, gb.x, gb.y);
        STV<BF>(out_, rowbase + c, o);
    }
}

__global__ __launch_bounds__(TPB, 8) void main_kernel(
    const void* hidden_, const void* W_in_, const void* b_in_,
    const void* W_out_, const void* b_out_, const void* wry_, const void* wrz_,
    const void* gamma_, const void* beta_, void* out_)
{
    __shared__ __align__(16) char smem[SMEM_BYTES];
    // dtype sniff: one ballot over the first 64 words of `hidden`
    const int lane = threadIdx.x & 63;
    unsigned wrd = ((const unsigned*)hidden_)[lane];
    unsigned lo  = wrd & 0xffffu;
    unsigned e   = (lo >> 7) & 0xffu;
    bool v = (lo == 0u) || (e >= 100u && e <= 133u);
    unsigned long long mask = __ballot(v);
    int flag = (__popcll(mask) > 32) ? 1 : 0;
    if (flag)
        run_all<1>(hidden_, W_in_, b_in_, W_out_, b_out_, wry_, wrz_,
                   gamma_, beta_, out_, smem);
    else
        run_all<0>(hidden_, W_in_, b_in_, W_out_, b_out_, wry_, wrz_,
                   gamma_, beta_, out_, smem);
}

extern "C" void kernel_launch(void* const* d_in, const int* in_sizes, int n_in,
                              void* d_out, int out_size, void* d_ws, size_t ws_size,
                              hipStream_t stream) {
    const void* hidden = d_in[0];
    const void* W_in   = d_in[1];
    const void* b_in   = d_in[2];
    const void* W_out  = d_in[3];
    const void* b_out  = d_in[4];
    const void* wry    = d_in[5];
    const void* wrz    = d_in[6];
    const void* gamma  = d_in[7];
    const void* beta   = d_in[8];
    (void)d_ws; (void)ws_size;
    main_kernel<<<NBLK, TPB, 0, stream>>>(hidden, W_in, b_in, W_out, b_out,
                                          wry, wrz, gamma, beta, d_out);
}